// Round 1
// baseline (346.346 us; speedup 1.0000x reference)
//
#include <hip/hip_runtime.h>

// Problem constants
#define BATCH 8
#define T_IN  262144
#define S_OUT 131072          // (T + 2*2 - 5)/2 + 1
#define EDIM  128
#define PDIM  64
#define KW    5

// Per-block tile: 64 s-positions x all 64 p, one batch.
// 4 waves/block; each wave: 16 s x 64 p, K=128 via 4 MFMA k-steps.

typedef __attribute__((ext_vector_type(8))) short short8;
typedef __attribute__((ext_vector_type(4))) float f32x4;

__device__ __forceinline__ short f2bf(float f) {
    unsigned u = __float_as_uint(f);
    unsigned r = (u + 0x7FFFu + ((u >> 16) & 1u)) >> 16;
    return (short)r;
}

__global__ __launch_bounds__(256)
void mm_encoder_kernel(const float* __restrict__ audio,
                       const float* __restrict__ conv_w,
                       const float* __restrict__ conv_b,
                       const float* __restrict__ lin_w,
                       const float* __restrict__ lin_b,
                       float* __restrict__ out) {
    __shared__ __align__(16) short fa[64][136];      // bf16 feats, +8 pad -> 2-way bank alias (free)
    __shared__ __align__(16) short wb[16][64][8];    // pre-swizzled B fragments [kt*4+nt][lane][j]
    __shared__ float xa[136];                        // padded audio segment

    const int tid  = threadIdx.x;
    const int bidx = blockIdx.x;
    const int b    = bidx >> 11;          // S_OUT/64 = 2048 s-tiles per batch
    const int s0   = (bidx & 2047) << 6;  // first s of this block

    // ---- Stage audio segment: xa[i] = x[b][2*s0 - 2 + i], zero-padded ----
    {
        const float* xb = audio + (long)b * T_IN;
        for (int i = tid; i < 136; i += 256) {
            int g = 2 * s0 - 2 + i;
            xa[i] = (g >= 0 && g < T_IN) ? xb[g] : 0.0f;
        }
    }

    // ---- Stage swizzled bf16 W fragments: wb[kt*4+nt][l][j] = lin_w[p][e] ----
    // p = nt*16 + (l&15), e = kt*32 + (l>>4)*8 + j
    for (int c = tid; c < 1024; c += 256) {
        int kt = c >> 8;
        int nt = (c >> 6) & 3;
        int l  = c & 63;
        int p  = nt * 16 + (l & 15);
        int e0 = kt * 32 + ((l >> 4) << 3);
        const float* src = lin_w + p * EDIM + e0;
        short8 v;
        #pragma unroll
        for (int j = 0; j < 8; ++j) v[j] = f2bf(src[j]);
        *(short8*)&wb[(kt << 2) + nt][l][0] = v;
    }

    __syncthreads();

    // ---- Conv + bias + relu -> bf16 feats in LDS ----
    // Each thread: fixed e-pair (e = 2*(tid&63)), s rows (tid>>6) + 4*it.
    {
        const int ep = tid & 63;
        const int e  = ep << 1;
        float w0[KW], w1[KW];
        #pragma unroll
        for (int k = 0; k < KW; ++k) {
            w0[k] = conv_w[e * KW + k];
            w1[k] = conv_w[(e + 1) * KW + k];
        }
        const float cb0 = conv_b[e];
        const float cb1 = conv_b[e + 1];
        const int sl0 = tid >> 6;
        #pragma unroll
        for (int it = 0; it < 16; ++it) {
            int sl = sl0 + (it << 2);
            float a0 = cb0, a1 = cb1;
            #pragma unroll
            for (int k = 0; k < KW; ++k) {
                float x = xa[2 * sl + k];   // wave-uniform address -> broadcast
                a0 = fmaf(w0[k], x, a0);
                a1 = fmaf(w1[k], x, a1);
            }
            a0 = fmaxf(a0, 0.0f);
            a1 = fmaxf(a1, 0.0f);
            int packed = ((int)(unsigned short)f2bf(a0)) | (((int)f2bf(a1)) << 16);
            *(int*)&fa[sl][e] = packed;
        }
    }

    __syncthreads();

    // ---- MFMA: each wave computes 16 s x 64 p ----
    const int wv   = tid >> 6;
    const int lane = tid & 63;
    const int quad = lane >> 4;
    const int m    = lane & 15;

    f32x4 acc0 = {0.f, 0.f, 0.f, 0.f};
    f32x4 acc1 = {0.f, 0.f, 0.f, 0.f};
    f32x4 acc2 = {0.f, 0.f, 0.f, 0.f};
    f32x4 acc3 = {0.f, 0.f, 0.f, 0.f};

    #pragma unroll
    for (int kt = 0; kt < 4; ++kt) {
        short8 a = *(const short8*)&fa[wv * 16 + m][kt * 32 + quad * 8];
        short8 b0 = *(const short8*)&wb[(kt << 2) + 0][lane][0];
        short8 b1 = *(const short8*)&wb[(kt << 2) + 1][lane][0];
        short8 b2 = *(const short8*)&wb[(kt << 2) + 2][lane][0];
        short8 b3 = *(const short8*)&wb[(kt << 2) + 3][lane][0];
        acc0 = __builtin_amdgcn_mfma_f32_16x16x32_bf16(a, b0, acc0, 0, 0, 0);
        acc1 = __builtin_amdgcn_mfma_f32_16x16x32_bf16(a, b1, acc1, 0, 0, 0);
        acc2 = __builtin_amdgcn_mfma_f32_16x16x32_bf16(a, b2, acc2, 0, 0, 0);
        acc3 = __builtin_amdgcn_mfma_f32_16x16x32_bf16(a, b3, acc3, 0, 0, 0);
    }

    // ---- Epilogue: out[b][s][p] = acc + lin_b[p] ----
    // C/D layout: col = lane&15 (p within n-tile), row = quad*4 + reg (s within wave tile)
    long obase = (long)b * S_OUT * PDIM + (long)(s0 + wv * 16) * PDIM;
    f32x4 accs[4] = {acc0, acc1, acc2, acc3};
    #pragma unroll
    for (int nt = 0; nt < 4; ++nt) {
        float lb = lin_b[nt * 16 + m];
        #pragma unroll
        for (int r = 0; r < 4; ++r) {
            int srow = quad * 4 + r;
            out[obase + (long)srow * PDIM + nt * 16 + m] = accs[nt][r] + lb;
        }
    }
}

extern "C" void kernel_launch(void* const* d_in, const int* in_sizes, int n_in,
                              void* d_out, int out_size, void* d_ws, size_t ws_size,
                              hipStream_t stream) {
    const float* audio  = (const float*)d_in[0];
    const float* conv_w = (const float*)d_in[1];
    const float* conv_b = (const float*)d_in[2];
    const float* lin_w  = (const float*)d_in[3];
    const float* lin_b  = (const float*)d_in[4];
    float* out = (float*)d_out;

    // 8 batches * 2048 s-tiles = 16384 blocks
    dim3 grid(BATCH * (S_OUT / 64));
    dim3 block(256);
    hipLaunchKernelGGL(mm_encoder_kernel, grid, block, 0, stream,
                       audio, conv_w, conv_b, lin_w, lin_b, out);
}

// Round 2
// 329.953 us; speedup vs baseline: 1.0497x; 1.0497x over previous
//
#include <hip/hip_runtime.h>

// Problem constants
#define BATCH 8
#define T_IN  262144
#define S_OUT 131072          // (T + 2*2 - 5)/2 + 1
#define EDIM  128
#define PDIM  64
#define KW    5
#define TILE_S 256            // s rows per block (4 subtiles of 64)
#define TILES_PER_B (S_OUT / TILE_S)   // 512

typedef __attribute__((ext_vector_type(8))) short short8;
typedef __attribute__((ext_vector_type(4))) float f32x4;

__device__ __forceinline__ short f2bf(float f) {
    unsigned u = __float_as_uint(f);
    unsigned r = (u + 0x7FFFu + ((u >> 16) & 1u)) >> 16;
    return (short)r;
}

__global__ __launch_bounds__(256)
void mm_encoder_kernel(const float* __restrict__ audio,
                       const float* __restrict__ conv_w,
                       const float* __restrict__ conv_b,
                       const float* __restrict__ lin_w,
                       const float* __restrict__ lin_b,
                       float* __restrict__ out) {
    __shared__ __align__(16) short fa[64][136];      // bf16 feats subtile, +8 pad
    __shared__ __align__(16) short wb[16][64][8];    // swizzled B fragments [kt*4+nt][lane][j]

    const int tid = threadIdx.x;
    const int b   = blockIdx.x >> 9;                   // 512 tiles per batch
    const int t0  = (blockIdx.x & (TILES_PER_B - 1)) << 8;

    // ---- Stage swizzled bf16 W fragments ONCE per block ----
    // p = nt*16 + (l&15), e = kt*32 + (l>>4)*8 + j
    for (int c = tid; c < 1024; c += 256) {
        int kt = c >> 8;
        int nt = (c >> 6) & 3;
        int l  = c & 63;
        int p  = nt * 16 + (l & 15);
        int e0 = kt * 32 + ((l >> 4) << 3);
        const float* src = lin_w + p * EDIM + e0;
        short8 v;
        #pragma unroll
        for (int j = 0; j < 8; ++j) v[j] = f2bf(src[j]);
        *(short8*)&wb[(kt << 2) + nt][l][0] = v;
    }

    const int wv   = tid >> 6;
    const int lane = tid & 63;
    const int quad = lane >> 4;
    const int m    = lane & 15;
    const int e    = lane << 1;

    // conv weights for this thread's e-pair (L1-resident after first block/CU)
    float w0[KW], w1[KW];
    #pragma unroll
    for (int k = 0; k < KW; ++k) {
        w0[k] = conv_w[e * KW + k];
        w1[k] = conv_w[(e + 1) * KW + k];
    }
    const float cb0 = conv_b[e];
    const float cb1 = conv_b[e + 1];
    float lbv[4];
    #pragma unroll
    for (int nt = 0; nt < 4; ++nt) lbv[nt] = lin_b[nt * 16 + m];

    const float* xb = audio + (long)b * T_IN;

    __syncthreads();   // wb visible to all waves; the ONLY barrier

    #pragma unroll 1
    for (int st = 0; st < 4; ++st) {
        const int srow0 = t0 + st * 64 + wv * 16;   // this thread's 16 consecutive s rows

        // ---- Load audio window [2*srow0-2, +36) into registers ----
        // Uniform per wave -> coalesced broadcast; edges zero-padded via clamp+select.
        float x[36];
        const int gbase = 2 * srow0 - 2;   // even
        #pragma unroll
        for (int j = 0; j < 18; ++j) {
            int g  = gbase + 2 * j;
            int gc = min(max(g, 0), T_IN - 2);
            float2 v = *(const float2*)(xb + gc);
            x[2 * j]     = ((unsigned)g < (unsigned)T_IN) ? v.x : 0.0f;
            x[2 * j + 1] = ((unsigned)(g + 1) < (unsigned)T_IN) ? v.y : 0.0f;
        }

        // ---- Conv + bias + relu, register sliding window ----
        int packed[16];
        #pragma unroll
        for (int r = 0; r < 16; ++r) {
            float a0 = cb0, a1 = cb1;
            #pragma unroll
            for (int k = 0; k < KW; ++k) {
                a0 = fmaf(w0[k], x[2 * r + k], a0);
                a1 = fmaf(w1[k], x[2 * r + k], a1);
            }
            a0 = fmaxf(a0, 0.0f);
            a1 = fmaxf(a1, 0.0f);
            packed[r] = ((int)(unsigned short)f2bf(a0)) | (((int)f2bf(a1)) << 16);
        }
        #pragma unroll
        for (int r = 0; r < 16; ++r)
            *(int*)&fa[wv * 16 + r][e] = packed[r];

        // Wave reads back only its OWN fa rows -> in-wave wait, no barrier.
        asm volatile("s_waitcnt lgkmcnt(0)" ::: "memory");

        // ---- MFMA: 16 s x 64 p, K=128 ----
        f32x4 acc[4] = {{0.f,0.f,0.f,0.f},{0.f,0.f,0.f,0.f},
                        {0.f,0.f,0.f,0.f},{0.f,0.f,0.f,0.f}};
        #pragma unroll
        for (int kt = 0; kt < 4; ++kt) {
            short8 a = *(const short8*)&fa[wv * 16 + m][kt * 32 + quad * 8];
            #pragma unroll
            for (int nt = 0; nt < 4; ++nt) {
                short8 bf = *(const short8*)&wb[(kt << 2) + nt][lane][0];
                acc[nt] = __builtin_amdgcn_mfma_f32_16x16x32_bf16(a, bf, acc[nt], 0, 0, 0);
            }
        }

        // ---- Epilogue: out[b][s][p] = acc + lin_b[p] ----
        // C/D layout: col = lane&15 (p), row = quad*4 + reg (s)
        long obase = (long)b * S_OUT * PDIM + (long)(srow0 + quad * 4) * PDIM;
        #pragma unroll
        for (int nt = 0; nt < 4; ++nt) {
            #pragma unroll
            for (int r = 0; r < 4; ++r) {
                out[obase + (long)r * PDIM + nt * 16 + m] = acc[nt][r] + lbv[nt];
            }
        }
    }
}

extern "C" void kernel_launch(void* const* d_in, const int* in_sizes, int n_in,
                              void* d_out, int out_size, void* d_ws, size_t ws_size,
                              hipStream_t stream) {
    const float* audio  = (const float*)d_in[0];
    const float* conv_w = (const float*)d_in[1];
    const float* conv_b = (const float*)d_in[2];
    const float* lin_w  = (const float*)d_in[3];
    const float* lin_b  = (const float*)d_in[4];
    float* out = (float*)d_out;

    // 8 batches * 512 tiles = 4096 blocks
    dim3 grid(BATCH * TILES_PER_B);
    dim3 block(256);
    hipLaunchKernelGGL(mm_encoder_kernel, grid, block, 0, stream,
                       audio, conv_w, conv_b, lin_w, lin_b, out);
}